// Round 4
// baseline (1163.385 us; speedup 1.0000x reference)
//
#include <hip/hip_runtime.h>

#define BATCH 8192

// ---------------------------------------------------------------------------
// Kernel 0: prep — transpose conv2 weights [16][72] -> w2t[72][16] (oc fastest,
// so 16 consecutive floats per (ic,k) enable s_load_dwordx16), and zero the
// BN partial buffer (replaces hipMemsetAsync).
// ---------------------------------------------------------------------------
__global__ __launch_bounds__(256) void prep(const float* __restrict__ c2w,
                                            float* __restrict__ w2t,
                                            float* __restrict__ partials) {
    int i = blockIdx.x * 256 + threadIdx.x;
    if (i < 1152) {
        int oc = i / 72, ick = i - oc * 72;
        w2t[ick * 16 + oc] = c2w[i];
    }
    if (i < 2048) partials[i] = 0.f;
}

// ---------------------------------------------------------------------------
// Kernel 1: per-sample fused conv1+pool+conv2+pool+v-dot+attention tail.
// One block = one sample, 256 threads.
// Register-blocked: conv threads own a spatial position and compute ALL
// output channels in registers; weights arrive via wave-uniform s_loads.
// ---------------------------------------------------------------------------
__global__ __launch_bounds__(256) void fused_fwd(
    const float* __restrict__ x,        // [B,1,28,28]
    const float* __restrict__ params,   // [B,4]
    const float* __restrict__ c1w,      // [8,1,3,3]
    const float* __restrict__ c1b,      // [8]
    const float* __restrict__ c2b,      // [16]
    const float* __restrict__ qkvw,     // [12,784]
    const float* __restrict__ qkvb,     // [12]
    const float* __restrict__ outw,     // [4,4]
    const float* __restrict__ outb,     // [4]
    const float* __restrict__ w2t,      // [72][16] transposed conv2 weights
    float* __restrict__ pre,            // ws: [B,4] pre-BN
    float* __restrict__ partials)       // ws: [256][8] (sum[4], sumsq[4])
{
    __shared__ float p1[8 * 256];    // padded pooled conv1 [8][16][16]
    __shared__ float uA[3200];       // union: xs[900] (conv1 in) / c2out[16][200]
    __shared__ float p2[784];        // pooled conv2 [16][7][7] flat
    __shared__ float vred[4][4];

    const int tid = threadIdx.x;
    const int b = blockIdx.x;
    float* xs = uA;
    float* c2out = uA;

    // ---- stage input (zero-padded 30x30), zero p1 border ----
    for (int i = tid; i < 900; i += 256) {
        int h = i / 30, w = i - h * 30;
        float v = 0.f;
        if (h >= 1 && h <= 28 && w >= 1 && w <= 28)
            v = x[b * 784 + (h - 1) * 28 + (w - 1)];
        xs[i] = v;
    }
    for (int i = tid; i < 2048; i += 256) p1[i] = 0.f;
    __syncthreads();

    // ---- conv1 (1->8) + relu + maxpool2: thread = pooled pos, 196 active ----
    {
        const int pos = tid < 196 ? tid : 195;   // clamp: uniform control flow
        const int ph = pos / 14, pw = pos - ph * 14;
        const float* base = &xs[(2 * ph) * 30 + 2 * pw];
        float in[4][4];
        #pragma unroll
        for (int r = 0; r < 4; ++r)
            #pragma unroll
            for (int c = 0; c < 4; ++c)
                in[r][c] = base[r * 30 + c];
        #pragma unroll
        for (int oc = 0; oc < 8; ++oc) {
            float m = 0.f;   // max(relu) == relu(max), and relu floor is 0
            #pragma unroll
            for (int dh = 0; dh < 2; ++dh)
                #pragma unroll
                for (int dw = 0; dw < 2; ++dw) {
                    float a = c1b[oc];
                    #pragma unroll
                    for (int r = 0; r < 3; ++r)
                        #pragma unroll
                        for (int c = 0; c < 3; ++c)
                            a += in[dh + r][dw + c] * c1w[oc * 9 + r * 3 + c];
                    m = fmaxf(m, a);
                }
            if (tid < 196) p1[oc * 256 + (ph + 1) * 16 + (pw + 1)] = m;
        }
    }
    __syncthreads();   // also fences xs before c2out overwrites it

    // ---- conv2 (8->16): thread = conv output pos (14x14), all 16 oc in regs ----
    {
        const int pos = tid < 196 ? tid : 195;
        const int h = pos / 14, w = pos - h * 14;
        const float* pbase = &p1[h * 16 + w];
        float acc[16];
        #pragma unroll
        for (int oc = 0; oc < 16; ++oc) acc[oc] = c2b[oc];
        #pragma unroll
        for (int ic = 0; ic < 8; ++ic) {
            const float i0 = pbase[ic * 256 + 0];
            const float i1 = pbase[ic * 256 + 1];
            const float i2 = pbase[ic * 256 + 2];
            const float i3 = pbase[ic * 256 + 16];
            const float i4 = pbase[ic * 256 + 17];
            const float i5 = pbase[ic * 256 + 18];
            const float i6 = pbase[ic * 256 + 32];
            const float i7 = pbase[ic * 256 + 33];
            const float i8 = pbase[ic * 256 + 34];
            const float* wr = &w2t[(ic * 9) * 16];
            #pragma unroll
            for (int oc = 0; oc < 16; ++oc) {
                acc[oc] += i0 * wr[0 * 16 + oc] + i1 * wr[1 * 16 + oc]
                         + i2 * wr[2 * 16 + oc] + i3 * wr[3 * 16 + oc]
                         + i4 * wr[4 * 16 + oc] + i5 * wr[5 * 16 + oc]
                         + i6 * wr[6 * 16 + oc] + i7 * wr[7 * 16 + oc]
                         + i8 * wr[8 * 16 + oc];
            }
        }
        #pragma unroll
        for (int oc = 0; oc < 16; ++oc)
            if (tid < 196) c2out[oc * 200 + pos] = fmaxf(acc[oc], 0.f);
    }
    __syncthreads();

    // ---- maxpool2 -> p2 [16][7][7] ----
    for (int it = tid; it < 784; it += 256) {
        int c = it / 49, r = it - c * 49;
        int ph = r / 7, pw = r - ph * 7;
        const float* pb = &c2out[c * 200 + (2 * ph) * 14 + 2 * pw];
        p2[it] = fmaxf(fmaxf(pb[0], pb[1]), fmaxf(pb[14], pb[15]));
    }
    __syncthreads();

    // ---- v = p2 . qkv_w[8..11] (q,k provably unused), float4 ----
    float v0 = 0.f, v1 = 0.f, v2 = 0.f, v3 = 0.f;
    if (tid < 196) {
        float4 f  = *(const float4*)&p2[tid * 4];
        float4 a0 = ((const float4*)&qkvw[8 * 784])[tid];
        float4 a1 = ((const float4*)&qkvw[9 * 784])[tid];
        float4 a2 = ((const float4*)&qkvw[10 * 784])[tid];
        float4 a3 = ((const float4*)&qkvw[11 * 784])[tid];
        v0 = f.x * a0.x + f.y * a0.y + f.z * a0.z + f.w * a0.w;
        v1 = f.x * a1.x + f.y * a1.y + f.z * a1.z + f.w * a1.w;
        v2 = f.x * a2.x + f.y * a2.y + f.z * a2.z + f.w * a2.w;
        v3 = f.x * a3.x + f.y * a3.y + f.z * a3.z + f.w * a3.w;
    }
    #pragma unroll
    for (int off = 32; off > 0; off >>= 1) {
        v0 += __shfl_xor(v0, off);
        v1 += __shfl_xor(v1, off);
        v2 += __shfl_xor(v2, off);
        v3 += __shfl_xor(v3, off);
    }
    if ((tid & 63) == 0) {
        const int wv = tid >> 6;
        vred[wv][0] = v0; vred[wv][1] = v1; vred[wv][2] = v2; vred[wv][3] = v3;
    }
    __syncthreads();

    // ---- tail: 4 lanes, one output channel each ----
    if (tid < 4) {
        float vv[4];
        #pragma unroll
        for (int j = 0; j < 4; ++j)
            vv[j] = vred[0][j] + vred[1][j] + vred[2][j] + vred[3][j] + qkvb[8 + j];

        float lg[4];
        float run = 1.f;
        #pragma unroll
        for (int j = 0; j < 4; ++j) { run *= cosf(params[b * 4 + j]); lg[j] = run; }
        float mx = fmaxf(fmaxf(lg[0], lg[1]), fmaxf(lg[2], lg[3]));
        float e[4], s = 0.f;
        #pragma unroll
        for (int j = 0; j < 4; ++j) { e[j] = expf(lg[j] - mx); s += e[j]; }
        float inv = 1.f / s;

        float t = outb[tid];
        #pragma unroll
        for (int j = 0; j < 4; ++j) t += outw[tid * 4 + j] * (e[j] * inv * vv[j]);
        pre[b * 4 + tid] = t;
        atomicAdd(&partials[(b & 255) * 8 + tid], t);
        atomicAdd(&partials[(b & 255) * 8 + 4 + tid], t * t);
    }
}

// ---------------------------------------------------------------------------
// Kernel 2: reduce 256 partial slots -> mu[4], inv_std[4]
// ---------------------------------------------------------------------------
__global__ __launch_bounds__(256) void bn_stats(
    const float* __restrict__ partials, float* __restrict__ stats)
{
    __shared__ float red[8][32];
    const int tid = threadIdx.x;
    const int val = tid & 7, grp = tid >> 3;
    float s = 0.f;
    for (int slot = grp; slot < 256; slot += 32) s += partials[slot * 8 + val];
    red[val][grp] = s;
    __syncthreads();
    if (tid < 8) {
        float t = 0.f;
        #pragma unroll
        for (int g = 0; g < 32; ++g) t += red[tid][g];
        red[tid][0] = t;
    }
    __syncthreads();
    if (tid < 4) {
        float mu  = red[tid][0] * (1.f / 8192.f);
        float var = red[tid + 4][0] * (1.f / 8192.f) - mu * mu;
        stats[tid]     = mu;
        stats[4 + tid] = rsqrtf(var + 1e-5f);
    }
}

// ---------------------------------------------------------------------------
// Kernel 3: apply BN
// ---------------------------------------------------------------------------
__global__ __launch_bounds__(256) void bn_apply(
    const float* __restrict__ pre, const float* __restrict__ stats,
    const float* __restrict__ gamma, const float* __restrict__ beta,
    float* __restrict__ out)
{
    const int i = blockIdx.x * 256 + threadIdx.x;
    const int c = i & 3;
    out[i] = (pre[i] - stats[c]) * stats[4 + c] * gamma[c] + beta[c];
}

extern "C" void kernel_launch(void* const* d_in, const int* in_sizes, int n_in,
                              void* d_out, int out_size, void* d_ws, size_t ws_size,
                              hipStream_t stream) {
    const float* x      = (const float*)d_in[0];
    const float* params = (const float*)d_in[1];
    const float* c1w    = (const float*)d_in[2];
    const float* c1b    = (const float*)d_in[3];
    const float* c2w    = (const float*)d_in[4];
    const float* c2b    = (const float*)d_in[5];
    const float* qkvw   = (const float*)d_in[6];
    const float* qkvb   = (const float*)d_in[7];
    const float* outw   = (const float*)d_in[8];
    const float* outb   = (const float*)d_in[9];
    const float* gamma  = (const float*)d_in[10];
    const float* beta   = (const float*)d_in[11];

    float* ws       = (float*)d_ws;
    float* w2t      = ws;                    // 1152 floats (64B-aligned base)
    float* pre      = ws + 1152;             // 32768 floats
    float* partials = ws + 1152 + 32768;     // 2048 floats
    float* stats    = ws + 1152 + 32768 + 2048;  // 8 floats

    prep<<<8, 256, 0, stream>>>(c2w, w2t, partials);
    fused_fwd<<<BATCH, 256, 0, stream>>>(x, params, c1w, c1b, c2b,
                                         qkvw, qkvb, outw, outb, w2t,
                                         pre, partials);
    bn_stats<<<1, 256, 0, stream>>>(partials, stats);
    bn_apply<<<32768 / 256, 256, 0, stream>>>(pre, stats, gamma, beta,
                                              (float*)d_out);
}

// Round 7
// 180.515 us; speedup vs baseline: 6.4448x; 6.4448x over previous
//
#include <hip/hip_runtime.h>

#define BATCH 8192

// ---------------------------------------------------------------------------
// Kernel 0: prep — reorder conv2 weights [16oc][8ic][3][3] -> w2r[(tap*8+ic)*16+oc]
// (oc fastest => 16 consecutive floats per step => 4 uniform float4 loads),
// and zero the BN partial buffer.
// ---------------------------------------------------------------------------
__global__ __launch_bounds__(256) void prep(const float* __restrict__ c2w,
                                            float* __restrict__ w2r,
                                            float* __restrict__ partials) {
    int i = blockIdx.x * 256 + threadIdx.x;
    if (i < 1152) {
        int oc  = i & 15;
        int tic = i >> 4;       // 0..71
        int ic  = tic & 7;
        int tap = tic >> 3;     // 0..8  (dh*3+dw)
        w2r[i] = c2w[oc * 72 + ic * 9 + tap];
    }
    if (i < 2048) partials[i] = 0.f;
}

// ---------------------------------------------------------------------------
// Kernel 1: per-sample fused conv1+pool+conv2+pool+v-dot+attention tail.
// One block = one sample, 256 threads.
// conv2: ROLLED (tap,ic) loop — 16 weight floats live per step (bounded SGPR
// pressure; round-4's full unroll needed 1152 and caused an AGPR spill storm).
// ---------------------------------------------------------------------------
__global__ __launch_bounds__(256, 4) void fused_fwd(
    const float* __restrict__ x,        // [B,1,28,28]
    const float* __restrict__ params,   // [B,4]
    const float* __restrict__ c1w,      // [8,1,3,3]
    const float* __restrict__ c1b,      // [8]
    const float* __restrict__ c2b,      // [16]
    const float* __restrict__ qkvw,     // [12,784]
    const float* __restrict__ qkvb,     // [12]
    const float* __restrict__ outw,     // [4,4]
    const float* __restrict__ outb,     // [4]
    const float* __restrict__ w2r,      // [72][16] reordered conv2 weights
    float* __restrict__ pre,            // ws: [B,4] pre-BN
    float* __restrict__ partials)       // ws: [256][8] (sum[4], sumsq[4])
{
    __shared__ __align__(16) float uA[3200];   // union: xs[900] / c2out[16][200]
    __shared__ __align__(16) float p1t[2304];  // [16*16 pos][9] (8 ic + 1 pad)
    __shared__ __align__(16) float p2[784];    // pooled conv2 [16][7][7]
    __shared__ float vred[4][4];

    const int tid = threadIdx.x;
    const int b = blockIdx.x;
    float* xs = uA;
    float* c2out = uA;

    // ---- stage input (zero-padded 30x30) + zero p1t ----
    for (int i = tid; i < 900; i += 256) {
        int h = i / 30, w = i - h * 30;
        float v = 0.f;
        if (h >= 1 && h <= 28 && w >= 1 && w <= 28)
            v = x[b * 784 + (h - 1) * 28 + (w - 1)];
        xs[i] = v;
    }
    for (int i = tid; i < 2304; i += 256) p1t[i] = 0.f;
    __syncthreads();

    // ---- conv1 (1->8) + relu + maxpool2: thread = pooled pos, 196 active ----
    // writes p1t[pos16x16][ic] position-major (stride 9, odd => conflict-lite)
    {
        const int pos = tid < 196 ? tid : 195;   // clamp: uniform control flow
        const int ph = pos / 14, pw = pos - ph * 14;
        const float* base = &xs[(2 * ph) * 30 + 2 * pw];
        float in[4][4];
        #pragma unroll
        for (int r = 0; r < 4; ++r)
            #pragma unroll
            for (int c = 0; c < 4; ++c)
                in[r][c] = base[r * 30 + c];
        const int obase = ((ph + 1) * 16 + (pw + 1)) * 9;
        #pragma unroll
        for (int oc = 0; oc < 8; ++oc) {
            float m = 0.f;   // max(relu) == relu(max); relu floor is 0
            #pragma unroll
            for (int dh = 0; dh < 2; ++dh)
                #pragma unroll
                for (int dw = 0; dw < 2; ++dw) {
                    float a = c1b[oc];
                    #pragma unroll
                    for (int r = 0; r < 3; ++r)
                        #pragma unroll
                        for (int c = 0; c < 3; ++c)
                            a += in[dh + r][dw + c] * c1w[oc * 9 + r * 3 + c];
                    m = fmaxf(m, a);
                }
            if (tid < 196) p1t[obase + oc] = m;
        }
    }
    __syncthreads();   // also last use of xs before c2out overwrites uA

    // ---- conv2 (8->16): thread = conv output pos (14x14), 16 oc in regs ----
    {
        const int pos = tid < 196 ? tid : 195;
        const int h = pos / 14, w = pos - h * 14;
        const int pbase = (h * 16 + w) * 9;

        float a0  = c2b[0],  a1  = c2b[1],  a2  = c2b[2],  a3  = c2b[3];
        float a4  = c2b[4],  a5  = c2b[5],  a6  = c2b[6],  a7  = c2b[7];
        float a8  = c2b[8],  a9  = c2b[9],  a10 = c2b[10], a11 = c2b[11];
        float a12 = c2b[12], a13 = c2b[13], a14 = c2b[14], a15 = c2b[15];

        const float* wp = w2r;
        #pragma unroll 1
        for (int dh = 0; dh < 3; ++dh) {
            #pragma unroll 1
            for (int dw = 0; dw < 3; ++dw) {
                const int ibase = pbase + (dh * 16 + dw) * 9;
                #pragma unroll 1
                for (int ic = 0; ic < 8; ++ic) {
                    const float iv = p1t[ibase + ic];
                    const float4 w0 = *(const float4*)(wp + 0);
                    const float4 w1 = *(const float4*)(wp + 4);
                    const float4 w2 = *(const float4*)(wp + 8);
                    const float4 w3 = *(const float4*)(wp + 12);
                    a0  += iv * w0.x;  a1  += iv * w0.y;
                    a2  += iv * w0.z;  a3  += iv * w0.w;
                    a4  += iv * w1.x;  a5  += iv * w1.y;
                    a6  += iv * w1.z;  a7  += iv * w1.w;
                    a8  += iv * w2.x;  a9  += iv * w2.y;
                    a10 += iv * w2.z;  a11 += iv * w2.w;
                    a12 += iv * w3.x;  a13 += iv * w3.y;
                    a14 += iv * w3.z;  a15 += iv * w3.w;
                    wp += 16;
                }
            }
        }
        if (tid < 196) {
            c2out[0  * 200 + pos] = fmaxf(a0,  0.f);
            c2out[1  * 200 + pos] = fmaxf(a1,  0.f);
            c2out[2  * 200 + pos] = fmaxf(a2,  0.f);
            c2out[3  * 200 + pos] = fmaxf(a3,  0.f);
            c2out[4  * 200 + pos] = fmaxf(a4,  0.f);
            c2out[5  * 200 + pos] = fmaxf(a5,  0.f);
            c2out[6  * 200 + pos] = fmaxf(a6,  0.f);
            c2out[7  * 200 + pos] = fmaxf(a7,  0.f);
            c2out[8  * 200 + pos] = fmaxf(a8,  0.f);
            c2out[9  * 200 + pos] = fmaxf(a9,  0.f);
            c2out[10 * 200 + pos] = fmaxf(a10, 0.f);
            c2out[11 * 200 + pos] = fmaxf(a11, 0.f);
            c2out[12 * 200 + pos] = fmaxf(a12, 0.f);
            c2out[13 * 200 + pos] = fmaxf(a13, 0.f);
            c2out[14 * 200 + pos] = fmaxf(a14, 0.f);
            c2out[15 * 200 + pos] = fmaxf(a15, 0.f);
        }
    }
    __syncthreads();

    // ---- maxpool2 -> p2 [16][7][7] ----
    for (int it = tid; it < 784; it += 256) {
        int c = it / 49, r = it - c * 49;
        int ph = r / 7, pw = r - ph * 7;
        const float* pb = &c2out[c * 200 + (2 * ph) * 14 + 2 * pw];
        p2[it] = fmaxf(fmaxf(pb[0], pb[1]), fmaxf(pb[14], pb[15]));
    }
    __syncthreads();

    // ---- v = p2 . qkv_w[8..11] (q,k provably unused), float4 ----
    float v0 = 0.f, v1 = 0.f, v2 = 0.f, v3 = 0.f;
    if (tid < 196) {
        float4 f  = *(const float4*)&p2[tid * 4];
        float4 a0 = ((const float4*)&qkvw[8 * 784])[tid];
        float4 a1 = ((const float4*)&qkvw[9 * 784])[tid];
        float4 a2 = ((const float4*)&qkvw[10 * 784])[tid];
        float4 a3 = ((const float4*)&qkvw[11 * 784])[tid];
        v0 = f.x * a0.x + f.y * a0.y + f.z * a0.z + f.w * a0.w;
        v1 = f.x * a1.x + f.y * a1.y + f.z * a1.z + f.w * a1.w;
        v2 = f.x * a2.x + f.y * a2.y + f.z * a2.z + f.w * a2.w;
        v3 = f.x * a3.x + f.y * a3.y + f.z * a3.z + f.w * a3.w;
    }
    #pragma unroll
    for (int off = 32; off > 0; off >>= 1) {
        v0 += __shfl_xor(v0, off);
        v1 += __shfl_xor(v1, off);
        v2 += __shfl_xor(v2, off);
        v3 += __shfl_xor(v3, off);
    }
    if ((tid & 63) == 0) {
        const int wv = tid >> 6;
        vred[wv][0] = v0; vred[wv][1] = v1; vred[wv][2] = v2; vred[wv][3] = v3;
    }
    __syncthreads();

    // ---- tail: 4 lanes, one output channel each ----
    if (tid < 4) {
        float vv[4];
        #pragma unroll
        for (int j = 0; j < 4; ++j)
            vv[j] = vred[0][j] + vred[1][j] + vred[2][j] + vred[3][j] + qkvb[8 + j];

        float lg[4];
        float run = 1.f;
        #pragma unroll
        for (int j = 0; j < 4; ++j) { run *= cosf(params[b * 4 + j]); lg[j] = run; }
        float mx = fmaxf(fmaxf(lg[0], lg[1]), fmaxf(lg[2], lg[3]));
        float e[4], s = 0.f;
        #pragma unroll
        for (int j = 0; j < 4; ++j) { e[j] = expf(lg[j] - mx); s += e[j]; }
        float inv = 1.f / s;

        float t = outb[tid];
        #pragma unroll
        for (int j = 0; j < 4; ++j) t += outw[tid * 4 + j] * (e[j] * inv * vv[j]);
        pre[b * 4 + tid] = t;
        atomicAdd(&partials[(b & 255) * 8 + tid], t);
        atomicAdd(&partials[(b & 255) * 8 + 4 + tid], t * t);
    }
}

// ---------------------------------------------------------------------------
// Kernel 2: reduce 256 partial slots -> mu[4], inv_std[4]
// ---------------------------------------------------------------------------
__global__ __launch_bounds__(256) void bn_stats(
    const float* __restrict__ partials, float* __restrict__ stats)
{
    __shared__ float red[8][32];
    const int tid = threadIdx.x;
    const int val = tid & 7, grp = tid >> 3;
    float s = 0.f;
    for (int slot = grp; slot < 256; slot += 32) s += partials[slot * 8 + val];
    red[val][grp] = s;
    __syncthreads();
    if (tid < 8) {
        float t = 0.f;
        #pragma unroll
        for (int g = 0; g < 32; ++g) t += red[tid][g];
        red[tid][0] = t;
    }
    __syncthreads();
    if (tid < 4) {
        float mu  = red[tid][0] * (1.f / 8192.f);
        float var = red[tid + 4][0] * (1.f / 8192.f) - mu * mu;
        stats[tid]     = mu;
        stats[4 + tid] = rsqrtf(var + 1e-5f);
    }
}

// ---------------------------------------------------------------------------
// Kernel 3: apply BN
// ---------------------------------------------------------------------------
__global__ __launch_bounds__(256) void bn_apply(
    const float* __restrict__ pre, const float* __restrict__ stats,
    const float* __restrict__ gamma, const float* __restrict__ beta,
    float* __restrict__ out)
{
    const int i = blockIdx.x * 256 + threadIdx.x;
    const int c = i & 3;
    out[i] = (pre[i] - stats[c]) * stats[4 + c] * gamma[c] + beta[c];
}

extern "C" void kernel_launch(void* const* d_in, const int* in_sizes, int n_in,
                              void* d_out, int out_size, void* d_ws, size_t ws_size,
                              hipStream_t stream) {
    const float* x      = (const float*)d_in[0];
    const float* params = (const float*)d_in[1];
    const float* c1w    = (const float*)d_in[2];
    const float* c1b    = (const float*)d_in[3];
    const float* c2w    = (const float*)d_in[4];
    const float* c2b    = (const float*)d_in[5];
    const float* qkvw   = (const float*)d_in[6];
    const float* qkvb   = (const float*)d_in[7];
    const float* outw   = (const float*)d_in[8];
    const float* outb   = (const float*)d_in[9];
    const float* gamma  = (const float*)d_in[10];
    const float* beta   = (const float*)d_in[11];

    float* ws       = (float*)d_ws;
    float* w2r      = ws;                        // 1152 floats
    float* pre      = ws + 1152;                 // 32768 floats
    float* partials = ws + 1152 + 32768;         // 2048 floats
    float* stats    = ws + 1152 + 32768 + 2048;  // 8 floats

    prep<<<8, 256, 0, stream>>>(c2w, w2r, partials);
    fused_fwd<<<BATCH, 256, 0, stream>>>(x, params, c1w, c1b, c2b,
                                         qkvw, qkvb, outw, outb, w2r,
                                         pre, partials);
    bn_stats<<<1, 256, 0, stream>>>(partials, stats);
    bn_apply<<<32768 / 256, 256, 0, stream>>>(pre, stats, gamma, beta,
                                              (float*)d_out);
}